// Round 11
// baseline (141.169 us; speedup 1.0000x reference)
//
#include <hip/hip_runtime.h>
#include <math.h>

#define NH 49152
#define KI 1024
#define DD 32
#define HF 256
#define REPB 768

typedef __attribute__((ext_vector_type(8))) short bf16x8;
typedef __attribute__((ext_vector_type(4))) float f32x4;

// float-index layout in ws
#define WS_PART  0                    // [0]=vrep [1]=vatt [2]=noise_sum [3]=n_noise(u32) [4]=sum(1-beta_a)
#define WS_SEG64 8                    // KI u64 packed (q_bits<<32 | NH-1-h)
#define WS_BH    2056                 // 12288 ushort (6144 floats): B-frag hi, [tile][kw][lane][r]
#define WS_BL    (WS_BH + 6144)       // 12288 ushort: B-frag lo
#define WS_A12   (WS_BL + 6144)       // KI*12: d0..7, ca, qa, pad2
#define WS_H12   (WS_A12 + 12*KI)     // NH*12: d0..7, ch, q, bc, pad
#define WS_XA    (WS_H12 + 12*NH)     // KI*DD full alpha coords
#define WS_OX    (WS_XA + KI*DD)      // NH*DD

__device__ __forceinline__ unsigned short bf16rne(float f) {
    unsigned u = __float_as_uint(f);
    unsigned r = u + 0x7FFFu + ((u >> 16) & 1u);
    return (unsigned short)(r >> 16);
}

// pack W as MFMA B-fragments (bf16 hi/lo split), fragment-major:
// idx = ((tile*8 + kw)*64 + lane)*8 + r ; value = B[k][n], k = kw*32+(lane>>4)*8+r,
// n = lane&15; tile0 = cols 0..15, tile1 = cols 16..31, tile2 = [Wb, 0...].
__global__ __launch_bounds__(256) void k_prep(const float* __restrict__ Wc,
                                              const float* __restrict__ Wb,
                                              float* __restrict__ ws) {
    const int i = blockIdx.x * 256 + threadIdx.x;
    if (i < 12288) {
        const int tile = i >> 12;
        const int r2 = i & 4095;
        const int kw = r2 >> 9;
        const int lr = r2 & 511;
        const int l = lr >> 3, r = lr & 7;
        const int k = kw * 32 + (l >> 4) * 8 + r;
        const int n = l & 15;
        float v;
        if (tile == 0)      v = Wc[(size_t)k * 32 + n];
        else if (tile == 1) v = Wc[(size_t)k * 32 + 16 + n];
        else                v = (n == 0) ? Wb[k] : 0.0f;
        const unsigned short hi = bf16rne(v);
        const float hf = __uint_as_float((unsigned)hi << 16);
        const unsigned short lo = bf16rne(v - hf);
        ((unsigned short*)(ws + WS_BH))[i] = hi;
        ((unsigned short*)(ws + WS_BL))[i] = lo;
    }
    if (i < 512) *(float4*)(ws + WS_SEG64 + (size_t)i * 4) = make_float4(0.f, 0.f, 0.f, 0.f);
    if (i < 8) ws[WS_PART + i] = 0.0f;
}

// GEMM on the MATRIX pipe: split-bf16 (xh+xl, Wh+Wl; drop xl*wl ~ 2^-18).
// wave = one 16-row tile; lane holds A[row=l&15][k=(l>>4)*8..+8] per 32-k window.
// All 8 x-windows loaded up-front (16 dwordx4 in flight) -> no LDS, no barriers.
__global__ __launch_bounds__(256, 3) void k_gemm(
        const float* __restrict__ x, const float* __restrict__ bb,
        const float* __restrict__ bcrd, const int* __restrict__ yi,
        float* __restrict__ ws) {
    const int t = threadIdx.x;
    const int w = t >> 6;
    const int l = t & 63;
    const int col = l & 15;
    const int kg  = l >> 4;
    const int h0 = blockIdx.x * 64 + w * 16;
    const unsigned short* __restrict__ bhp = (const unsigned short*)(ws + WS_BH);
    const unsigned short* __restrict__ blp = (const unsigned short*)(ws + WS_BL);
    const float* __restrict__ xp = x + (size_t)(h0 + col) * HF + kg * 8;

    // load ALL x windows up-front: 16 dwordx4 outstanding, latency fully hidden
    float4 xv[8][2];
    #pragma unroll
    for (int kw = 0; kw < 8; ++kw) {
        xv[kw][0] = *(const float4*)(xp + kw * 32);
        xv[kw][1] = *(const float4*)(xp + kw * 32 + 4);
    }

    f32x4 a0 = {0.f, 0.f, 0.f, 0.f};
    f32x4 a1 = {0.f, 0.f, 0.f, 0.f};
    f32x4 a2 = {0.f, 0.f, 0.f, 0.f};

    #pragma unroll
    for (int kw = 0; kw < 8; ++kw) {
        const int base = (kw * 64 + l) * 8;
        const bf16x8 B0h = *(const bf16x8*)(bhp + base);
        const bf16x8 B0l = *(const bf16x8*)(blp + base);
        const bf16x8 B1h = *(const bf16x8*)(bhp + 4096 + base);
        const bf16x8 B1l = *(const bf16x8*)(blp + 4096 + base);
        const bf16x8 B2h = *(const bf16x8*)(bhp + 8192 + base);
        const bf16x8 B2l = *(const bf16x8*)(blp + 8192 + base);

        bf16x8 Ah, Al;
        const float* xf = (const float*)&xv[kw][0];
        #pragma unroll
        for (int r = 0; r < 8; ++r) {
            const float v = xf[r];
            const unsigned short hi = bf16rne(v);
            const float hf = __uint_as_float((unsigned)hi << 16);
            const unsigned short lo = bf16rne(v - hf);
            Ah[r] = (short)hi;
            Al[r] = (short)lo;
        }
        a0 = __builtin_amdgcn_mfma_f32_16x16x32_bf16(Ah, B0h, a0, 0, 0, 0);
        a1 = __builtin_amdgcn_mfma_f32_16x16x32_bf16(Ah, B1h, a1, 0, 0, 0);
        a2 = __builtin_amdgcn_mfma_f32_16x16x32_bf16(Ah, B2h, a2, 0, 0, 0);
        a0 = __builtin_amdgcn_mfma_f32_16x16x32_bf16(Ah, B0l, a0, 0, 0, 0);
        a1 = __builtin_amdgcn_mfma_f32_16x16x32_bf16(Ah, B1l, a1, 0, 0, 0);
        a2 = __builtin_amdgcn_mfma_f32_16x16x32_bf16(Ah, B2l, a2, 0, 0, 0);
        a0 = __builtin_amdgcn_mfma_f32_16x16x32_bf16(Al, B0h, a0, 0, 0, 0);
        a1 = __builtin_amdgcn_mfma_f32_16x16x32_bf16(Al, B1h, a1, 0, 0, 0);
        a2 = __builtin_amdgcn_mfma_f32_16x16x32_bf16(Al, B2h, a2, 0, 0, 0);
    }

    // epilogue: C layout col = l&15, row = (l>>4)*4 + r  (m89-verified)
    const float bc0 = bcrd[col];
    const float bc1 = bcrd[16 + col];
    const float bb0 = bb[0];
    float nb = 0.0f;
    unsigned cnt = 0u;
    #pragma unroll
    for (int r = 0; r < 4; ++r) {
        const int h = h0 + kg * 4 + r;
        const float o0 = a0[r] + bc0;
        const float o1 = a1[r] + bc1;
        ws[WS_OX + (size_t)h * DD + col]      = o0;
        ws[WS_OX + (size_t)h * DD + 16 + col] = o1;
        float sq = (col < 8) ? o0 * o0 : 0.0f;
        sq += __shfl_xor(sq, 1);
        sq += __shfl_xor(sq, 2);
        sq += __shfl_xor(sq, 4);
        sq += __shfl_xor(sq, 8);
        if (col < 8) ws[WS_H12 + (size_t)h * 12 + col] = o0;
        if (col == 0) {
            float* hr = ws + WS_H12 + (size_t)h * 12;
            hr[8] = 0.5f * sq;
            const float z    = a2[r] + bb0;
            const float beta = 1.0f / (1.0f + expf(-z));
            const float bcv  = fminf(fmaxf(beta, 1e-4f), 0.9999f);
            const float at   = atanhf(bcv);
            hr[9]  = at * at + 0.5f;
            hr[10] = bcv;
            const int y = yi[h];
            if (y < 0) { nb += bcv; cnt += 1u; }
        }
    }
    for (int off = 32; off > 0; off >>= 1) {
        nb  += __shfl_down(nb, off);
        cnt += __shfl_down(cnt, off);
    }
    if (l == 0) {
        atomicAdd(ws + WS_PART + 2, nb);
        atomicAdd((unsigned int*)(ws + WS_PART + 3), cnt);
    }
}

// fused segment argmax: pack (q_bits, NH-1-h) -> one u64 atomicMax.
__global__ __launch_bounds__(256) void k_segmax(const int* __restrict__ eh, const int* __restrict__ ei,
                                                int E, const float* __restrict__ h12,
                                                unsigned long long* __restrict__ seg) {
    int e = blockIdx.x * 256 + threadIdx.x;
    if (e < E) {
        int h = eh[e];
        float q = h12[(size_t)h * 12 + 9];
        unsigned long long pk = ((unsigned long long)__float_as_uint(q) << 32)
                              | (unsigned)(NH - 1 - h);
        atomicMax(seg + ei[e], pk);
    }
}

__global__ __launch_bounds__(256) void k_gather(float* __restrict__ ws) {
    const int k = blockIdx.x * 256 + threadIdx.x;
    unsigned long long pk = ((const unsigned long long*)(ws + WS_SEG64))[k];
    int a = NH - 1 - (int)(unsigned)(pk & 0xffffffffu);
    a = max(0, min(a, NH - 1));
    float4 v0, v1;
    float s8 = 0.0f;
    #pragma unroll
    for (int d0 = 0; d0 < DD; d0 += 4) {
        float4 v = *(const float4*)(ws + WS_OX + (size_t)a * DD + d0);
        *(float4*)(ws + WS_XA + (size_t)k * DD + d0) = v;
        if (d0 == 0) { v0 = v; s8 += v.x*v.x + v.y*v.y + v.z*v.z + v.w*v.w; }
        if (d0 == 4) { v1 = v; s8 += v.x*v.x + v.y*v.y + v.z*v.z + v.w*v.w; }
    }
    *(float4*)(ws + WS_A12 + (size_t)k * 12)     = v0;
    *(float4*)(ws + WS_A12 + (size_t)k * 12 + 4) = v1;
    ws[WS_A12 + (size_t)k * 12 + 8] = 0.5f * (s8 - 1.0f);                    // ca
    ws[WS_A12 + (size_t)k * 12 + 9] = ws[WS_H12 + (size_t)a * 12 + 9];       // qa
    float omba = 1.0f - ws[WS_H12 + (size_t)a * 12 + 10];
    for (int off = 32; off > 0; off >>= 1) omba += __shfl_down(omba, off);
    if ((threadIdx.x & 63) == 0) atomicAdd(ws + WS_PART + 4, omba);
}

// merged v_att + v_rep (single launch; blocks [0,REPB) = rep, rest = att)
__global__ __launch_bounds__(256, 4) void k_attrep(
        const int* __restrict__ eh, const int* __restrict__ ei, int E,
        const int* __restrict__ yi, float* __restrict__ ws) {
    __shared__ float al[128 * 12];
    __shared__ float red[4];
    const float* __restrict__ a12 = ws + WS_A12;
    const float* __restrict__ h12 = ws + WS_H12;
    const float* __restrict__ ox  = ws + WS_OX;
    const float* __restrict__ xa  = ws + WS_XA;
    const int t = threadIdx.x;

    if (blockIdx.x >= REPB) {
        // ---- attractive: one edge per thread ----
        const int e = (blockIdx.x - REPB) * 256 + t;
        float cv = 0.0f;
        if (e < E) {
            const int h = eh[e], k = ei[e];
            const float* a = ox + (size_t)h * DD;
            const float* b = xa + (size_t)k * DD;
            float d2 = 0.0f;
            #pragma unroll
            for (int d0 = 0; d0 < DD; d0 += 4) {
                float4 av = *(const float4*)(a + d0);
                float4 bv = *(const float4*)(b + d0);
                float dx = av.x - bv.x; d2 = fmaf(dx, dx, d2);
                float dy = av.y - bv.y; d2 = fmaf(dy, dy, d2);
                float dz = av.z - bv.z; d2 = fmaf(dz, dz, d2);
                float dw = av.w - bv.w; d2 = fmaf(dw, dw, d2);
            }
            cv = h12[(size_t)h * 12 + 9] * a12[(size_t)k * 12 + 9] * d2;
        }
        for (int off = 32; off > 0; off >>= 1) cv += __shfl_down(cv, off);
        if ((t & 63) == 0) red[t >> 6] = cv;
        __syncthreads();
        if (t == 0) atomicAdd(ws + WS_PART + 1, red[0] + red[1] + red[2] + red[3]);
        return;
    }

    // ---- repulsive: 512 hits x 128 alphas per block; exact 8-dim filter ----
    const int bh = blockIdx.x % 96;
    const int bk = blockIdx.x / 96;
    const int k0 = bk * 128;
    for (int i = t; i < 128 * 12; i += 256)
        al[i] = a12[(size_t)k0 * 12 + i];
    __syncthreads();

    const int h1 = bh * 512 + t;
    const int h2 = h1 + 256;
    const float4 p0  = *(const float4*)(h12 + (size_t)h1 * 12);
    const float4 p1  = *(const float4*)(h12 + (size_t)h1 * 12 + 4);
    const float2 cq1 = *(const float2*)(h12 + (size_t)h1 * 12 + 8);
    const float4 s0  = *(const float4*)(h12 + (size_t)h2 * 12);
    const float4 s1  = *(const float4*)(h12 + (size_t)h2 * 12 + 4);
    const float2 cq2 = *(const float2*)(h12 + (size_t)h2 * 12 + 8);
    const int yh1 = yi[h1], yh2 = yi[h2];
    float loc = 0.0f;

    #pragma unroll 4
    for (int r = 0; r < 128; ++r) {
        const float4 b0  = *(const float4*)(al + r * 12);
        const float4 b1  = *(const float4*)(al + r * 12 + 4);
        const float2 bcq = *(const float2*)(al + r * 12 + 8);
        float acc1 = -cq1.x - bcq.x;
        acc1 = fmaf(p0.x, b0.x, acc1);
        acc1 = fmaf(p0.y, b0.y, acc1);
        acc1 = fmaf(p0.z, b0.z, acc1);
        acc1 = fmaf(p0.w, b0.w, acc1);
        acc1 = fmaf(p1.x, b1.x, acc1);
        acc1 = fmaf(p1.y, b1.y, acc1);
        acc1 = fmaf(p1.z, b1.z, acc1);
        acc1 = fmaf(p1.w, b1.w, acc1);
        float acc2 = -cq2.x - bcq.x;
        acc2 = fmaf(s0.x, b0.x, acc2);
        acc2 = fmaf(s0.y, b0.y, acc2);
        acc2 = fmaf(s0.z, b0.z, acc2);
        acc2 = fmaf(s0.w, b0.w, acc2);
        acc2 = fmaf(s1.x, b1.x, acc2);
        acc2 = fmaf(s1.y, b1.y, acc2);
        acc2 = fmaf(s1.z, b1.z, acc2);
        acc2 = fmaf(s1.w, b1.w, acc2);
        if (acc1 > 0.0f) {          // rare: d2 over first 8 dims < 1
            const int kg = k0 + r;
            if (yh1 != kg) {
                float d2 = 1.0f - 2.0f * acc1;
                const float* hp  = ox + (size_t)h1 * DD;
                const float* apf = xa + (size_t)kg * DD;
                #pragma unroll
                for (int d = 8; d < DD; d += 4) {
                    float4 av = *(const float4*)(hp + d);
                    float4 bv = *(const float4*)(apf + d);
                    float dx = av.x - bv.x; d2 = fmaf(dx, dx, d2);
                    float dy = av.y - bv.y; d2 = fmaf(dy, dy, d2);
                    float dz = av.z - bv.z; d2 = fmaf(dz, dz, d2);
                    float dw = av.w - bv.w; d2 = fmaf(dw, dw, d2);
                }
                float dist = sqrtf(fmaxf(d2, 0.0f) + 1e-12f);
                float hin  = 1.0f - dist;
                if (hin > 0.0f) loc += cq1.y * bcq.y * hin;
            }
        }
        if (acc2 > 0.0f) {
            const int kg = k0 + r;
            if (yh2 != kg) {
                float d2 = 1.0f - 2.0f * acc2;
                const float* hp  = ox + (size_t)h2 * DD;
                const float* apf = xa + (size_t)kg * DD;
                #pragma unroll
                for (int d = 8; d < DD; d += 4) {
                    float4 av = *(const float4*)(hp + d);
                    float4 bv = *(const float4*)(apf + d);
                    float dx = av.x - bv.x; d2 = fmaf(dx, dx, d2);
                    float dy = av.y - bv.y; d2 = fmaf(dy, dy, d2);
                    float dz = av.z - bv.z; d2 = fmaf(dz, dz, d2);
                    float dw = av.w - bv.w; d2 = fmaf(dw, dw, d2);
                }
                float dist = sqrtf(fmaxf(d2, 0.0f) + 1e-12f);
                float hin  = 1.0f - dist;
                if (hin > 0.0f) loc += cq2.y * bcq.y * hin;
            }
        }
    }
    for (int off = 32; off > 0; off >>= 1) loc += __shfl_down(loc, off);
    if ((t & 63) == 0) red[t >> 6] = loc;
    __syncthreads();
    if (t == 0) atomicAdd(ws + WS_PART + 0, red[0] + red[1] + red[2] + red[3]);
}

__global__ void k_final(const float* __restrict__ temp, float* __restrict__ ws,
                        float* __restrict__ out) {
    float vrep  = ws[WS_PART + 0];
    float vatt  = ws[WS_PART + 1];
    float nsum  = ws[WS_PART + 2];
    unsigned nn = *(const unsigned int*)(ws + WS_PART + 3);
    float somba = ws[WS_PART + 4];
    float lb = somba * (1.0f / (float)KI) + nsum / (float)(nn < 1u ? 1u : nn);
    float lv = (vatt + vrep) / (float)NH;
    float tv = temp[0];
    out[0] = (lb + lv) * expf(-tv) + tv;
}

extern "C" void kernel_launch(void* const* d_in, const int* in_sizes, int n_in,
                              void* d_out, int out_size, void* d_ws, size_t ws_size,
                              hipStream_t stream) {
    const float* x    = (const float*)d_in[0];
    const float* Wb   = (const float*)d_in[1];
    const float* bb   = (const float*)d_in[2];
    const float* Wc   = (const float*)d_in[3];
    const float* bcrd = (const float*)d_in[4];
    const float* temp = (const float*)d_in[5];
    const int*   yi   = (const int*)d_in[6];
    const int*   ep   = (const int*)d_in[8];
    const int E = in_sizes[8] / 2;
    const int* eh = ep;
    const int* ei = ep + E;
    float* ws  = (float*)d_ws;
    float* out = (float*)d_out;

    k_prep<<<48, 256, 0, stream>>>(Wc, Wb, ws);
    k_gemm<<<NH / 64, 256, 0, stream>>>(x, bb, bcrd, yi, ws);
    const int eb = (E + 255) / 256;
    k_segmax<<<eb, 256, 0, stream>>>(eh, ei, E, ws + WS_H12,
                                     (unsigned long long*)(ws + WS_SEG64));
    k_gather<<<KI / 256, 256, 0, stream>>>(ws);
    k_attrep<<<REPB + eb, 256, 0, stream>>>(eh, ei, E, yi, ws);
    k_final<<<1, 1, 0, stream>>>(temp, ws, out);
}